// Round 3
// baseline (360.541 us; speedup 1.0000x reference)
//
#include <hip/hip_runtime.h>

#define N_EDGES 1600000
#define N_NODES 50000
#define D_FEAT  32

// ---- workspace layout (bytes) ----
// offs:   int[N_NODES+1]
// cursor: int[N_NODES]
// perm:   int[N_EDGES]
#define OFFS_BYTES   ((N_NODES + 1) * 4)
#define CURSOR_OFF   ((size_t)(((OFFS_BYTES + 255) / 256) * 256))
#define PERM_OFF     (CURSOR_OFF + (size_t)(((N_NODES * 4 + 255) / 256) * 256))
#define WS_NEEDED    (PERM_OFF + (size_t)N_EDGES * 4)

__global__ void zero_counts_kernel(int* __restrict__ cnt) {
    int i = blockIdx.x * blockDim.x + threadIdx.x;
    if (i <= N_NODES) cnt[i] = 0;
}

// Histogram: counts[node] = #edges. int4-vectorized index read.
__global__ void hist_kernel(const int4* __restrict__ index4,
                            int* __restrict__ cnt) {
    int t = blockIdx.x * blockDim.x + threadIdx.x;
    const int n4 = N_EDGES / 4;
    if (t >= n4) return;
    int4 v = index4[t];
    atomicAdd(&cnt[v.x], 1);
    atomicAdd(&cnt[v.y], 1);
    atomicAdd(&cnt[v.z], 1);
    atomicAdd(&cnt[v.w], 1);
}

// Single-block exclusive scan: counts -> offsets; also writes cursor = offsets.
__global__ __launch_bounds__(1024) void scan_offsets_kernel(int* __restrict__ cnt,
                                                            int* __restrict__ cursor) {
    const int T = 1024;
    const int C = (N_NODES + T - 1) / T;  // 49 per thread
    __shared__ int part[T];
    int t = threadIdx.x;
    int base = t * C;
    int s = 0;
    for (int j = 0; j < C; ++j) {
        int i = base + j;
        if (i < N_NODES) s += cnt[i];
    }
    part[t] = s;
    __syncthreads();
    int v = s;
    for (int d = 1; d < T; d <<= 1) {
        int w = (t >= d) ? part[t - d] : 0;
        __syncthreads();
        v += w;
        part[t] = v;
        __syncthreads();
    }
    int run = v - s;
    for (int j = 0; j < C; ++j) {
        int i = base + j;
        if (i < N_NODES) {
            int c = cnt[i];
            cnt[i] = run;
            cursor[i] = run;
            run += c;
        }
    }
    if (t == T - 1) cnt[N_NODES] = v;
}

// Fused rank+perm: perm[cursor[node]++] = e  (order within segment arbitrary).
__global__ void scatter_perm_kernel(const int4* __restrict__ index4,
                                    int* __restrict__ cursor,
                                    int* __restrict__ perm) {
    int t = blockIdx.x * blockDim.x + threadIdx.x;
    const int n4 = N_EDGES / 4;
    if (t >= n4) return;
    int4 v = index4[t];
    int e = t * 4;
    perm[atomicAdd(&cursor[v.x], 1)] = e + 0;
    perm[atomicAdd(&cursor[v.y], 1)] = e + 1;
    perm[atomicAdd(&cursor[v.z], 1)] = e + 2;
    perm[atomicAdd(&cursor[v.w], 1)] = e + 3;
}

// One 64-lane wave per node. lane = slot*8 + f4: 8 edge-slots x 8 float4-lanes.
// 8 concurrent edges/wave, 2-deep unroll -> up to 16 independent 128B row loads
// in flight per wave. Reduce across slots with shfl_xor(8,16,32); 128B store.
__global__ void gather_sum_kernel(const float4* __restrict__ src4,
                                  const int* __restrict__ perm,
                                  const int* __restrict__ offs,
                                  const float4* __restrict__ out_in4,
                                  float4* __restrict__ out4) {
    int wave = threadIdx.x >> 6;            // 4 waves / 256-thread block
    int node = blockIdx.x * 4 + wave;
    if (node >= N_NODES) return;
    int lane = threadIdx.x & 63;
    int slot = lane >> 3;                   // 0..7
    int f4   = lane & 7;                    // 0..7 (float4 within 32-feat row)
    int start = offs[node];
    int end   = offs[node + 1];

    float4 a0 = {0.f, 0.f, 0.f, 0.f};
    float4 a1 = {0.f, 0.f, 0.f, 0.f};
    int i = start + slot;
    for (; i + 8 < end; i += 16) {
        int e0 = perm[i];
        int e1 = perm[i + 8];
        float4 v0 = src4[(size_t)e0 * 8 + f4];
        float4 v1 = src4[(size_t)e1 * 8 + f4];
        a0.x += v0.x; a0.y += v0.y; a0.z += v0.z; a0.w += v0.w;
        a1.x += v1.x; a1.y += v1.y; a1.z += v1.z; a1.w += v1.w;
    }
    if (i < end) {
        int e0 = perm[i];
        float4 v0 = src4[(size_t)e0 * 8 + f4];
        a0.x += v0.x; a0.y += v0.y; a0.z += v0.z; a0.w += v0.w;
    }
    a0.x += a1.x; a0.y += a1.y; a0.z += a1.z; a0.w += a1.w;

    for (int m = 8; m <= 32; m <<= 1) {
        a0.x += __shfl_xor(a0.x, m, 64);
        a0.y += __shfl_xor(a0.y, m, 64);
        a0.z += __shfl_xor(a0.z, m, 64);
        a0.w += __shfl_xor(a0.w, m, 64);
    }
    if (slot == 0) {
        size_t o = (size_t)node * 8 + f4;
        float4 b = out_in4[o];
        b.x += a0.x; b.y += a0.y; b.z += a0.z; b.w += a0.w;
        out4[o] = b;
    }
}

// ---- fallback (round-1 proven path) if ws is too small ----
__global__ void init_out_kernel(const float4* __restrict__ out_in,
                                float4* __restrict__ out, int n4) {
    int i = blockIdx.x * blockDim.x + threadIdx.x;
    int stride = gridDim.x * blockDim.x;
    for (; i < n4; i += stride) out[i] = out_in[i];
}
__global__ void scatter_add_kernel(const float4* __restrict__ src,
                                   const int* __restrict__ index,
                                   float* __restrict__ out) {
    const int total = N_EDGES * 8;
    int t = blockIdx.x * blockDim.x + threadIdx.x;
    int stride = gridDim.x * blockDim.x;
    for (; t < total; t += stride) {
        int e = t >> 3;
        int f = t & 7;
        float4 v = src[t];
        int node = index[e];
        float* o = out + (size_t)node * D_FEAT + f * 4;
        atomicAdd(o + 0, v.x);
        atomicAdd(o + 1, v.y);
        atomicAdd(o + 2, v.z);
        atomicAdd(o + 3, v.w);
    }
}

extern "C" void kernel_launch(void* const* d_in, const int* in_sizes, int n_in,
                              void* d_out, int out_size, void* d_ws, size_t ws_size,
                              hipStream_t stream) {
    const float* src    = (const float*)d_in[0];
    const int*   index  = (const int*)d_in[1];
    const float* out_in = (const float*)d_in[2];
    float* out          = (float*)d_out;

    if (ws_size < WS_NEEDED) {
        int n4 = out_size / 4;
        init_out_kernel<<<2048, 256, 0, stream>>>((const float4*)out_in, (float4*)out, n4);
        scatter_add_kernel<<<2048, 256, 0, stream>>>((const float4*)src, index, out);
        return;
    }

    char* ws = (char*)d_ws;
    int* offs   = (int*)ws;
    int* cursor = (int*)(ws + CURSOR_OFF);
    int* perm   = (int*)(ws + PERM_OFF);

    const int n4 = N_EDGES / 4;
    zero_counts_kernel<<<(N_NODES + 256) / 256, 256, 0, stream>>>(offs);
    hist_kernel<<<(n4 + 255) / 256, 256, 0, stream>>>((const int4*)index, offs);
    scan_offsets_kernel<<<1, 1024, 0, stream>>>(offs, cursor);
    scatter_perm_kernel<<<(n4 + 255) / 256, 256, 0, stream>>>((const int4*)index, cursor, perm);
    gather_sum_kernel<<<(N_NODES + 3) / 4, 256, 0, stream>>>(
        (const float4*)src, perm, offs, (const float4*)out_in, (float4*)out);
}